// Round 12
// baseline (709.875 us; speedup 1.0000x reference)
//
#include <hip/hip_runtime.h>
#include <hip/hip_bf16.h>
#include <math.h>

#define DIM 896
#define DD  (DIM * DIM)
#define NH 8
#define HD 112
#define BB 64
#define TT 8
#define KA 65
#define KAPAD 4224   // 64*65 = 4160 padded to 33*128
#define KT 512
#define NKEYS (TT + KA + KT)   // 585

#define EPI_NONE  0
#define EPI_ROPE  1
#define EPI_RESID 2
#define EPI_RELU  3

// -log2(10000)/56
#define NEG_L2_10K_OVER_56 (-0.2373327285062406f)

#ifndef __has_builtin
#define __has_builtin(x) 0
#endif
#if __has_builtin(__builtin_amdgcn_global_load_lds)
#define HAS_GLL 1
#else
#define HAS_GLL 0
#endif

typedef __attribute__((ext_vector_type(8))) short bf16x8_t;   // 8 bf16 (4 VGPRs)
typedef __attribute__((ext_vector_type(4))) float f32x4_t;    // MFMA accumulator

__device__ __forceinline__ short f2bf(float f) {
  unsigned u = __float_as_uint(f);
  u += 0x7fffu + ((u >> 16) & 1u);
  return (short)(u >> 16);
}
__device__ __forceinline__ float bf2f(short s) {
  return __uint_as_float(((unsigned)(unsigned short)s) << 16);
}
// 2x f32 -> packed bf16 pair (RNE; bit-identical to f2bf for normals).
__device__ __forceinline__ unsigned cvt_pk_bf16(float lo, float hi) {
  unsigned r;
  asm("v_cvt_pk_bf16_f32 %0, %1, %2" : "=v"(r) : "v"(lo), "v"(hi));
  return r;
}
// 16-B global -> LDS direct copy. dest = lbase + lane*16B (wave-uniform base).
__device__ __forceinline__ void gll16(const short* g, short* lbase, int lane) {
#if HAS_GLL
  __builtin_amdgcn_global_load_lds(
      (const __attribute__((address_space(1))) unsigned*)g,
      (__attribute__((address_space(3))) unsigned*)lbase, 16, 0, 0);
#else
  *(bf16x8_t*)(lbase + lane * 8) = *(const bf16x8_t*)g;
#endif
}

// ---------------- 9-way weight transpose: W[k][n] f32 -> Wt[n][k] bf16 ----------------
struct W9 { const float* w[9]; };

__global__ __launch_bounds__(256) void wtrans(W9 ws, short* __restrict__ Wt)
{
  __shared__ float t[32][33];
  const float* W = ws.w[blockIdx.z];
  short* dst = Wt + (size_t)blockIdx.z * DD;
  const int bx = blockIdx.x, by = blockIdx.y;
  const int tx = threadIdx.x & 31, ty = threadIdx.x >> 5;
#pragma unroll
  for (int i = 0; i < 4; ++i)
    t[ty + i * 8][tx] = W[(size_t)(by * 32 + ty + i * 8) * DIM + bx * 32 + tx];
  __syncthreads();
#pragma unroll
  for (int i = 0; i < 4; ++i)
    dst[(size_t)(bx * 32 + ty + i * 8) * DIM + by * 32 + tx] = f2bf(t[tx][ty + i * 8]);
}

// ---------------- h_ad = concat(h_a, p) -> bf16, zero-padded to 4224 rows ----------------
__global__ __launch_bounds__(256) void build_had(
    const float* __restrict__ h_a, const float* __restrict__ p,
    short* __restrict__ had)
{
  const int i = blockIdx.x * 256 + threadIdx.x;  // one per 8 elements
  const int total = KAPAD * DIM / 8;
  if (i >= total) return;
  const int c = (i % 112) * 8;
  const int row = i / 112;
  bf16x8_t o;
  if (row >= BB * KA) {
#pragma unroll
    for (int j = 0; j < 8; ++j) o[j] = 0;
  } else {
    const int b = row / KA, j = row % KA;
    const float* src = (j < KA - 1) ? h_a + ((size_t)b * (KA - 1) + j) * DIM + c
                                    : p + (size_t)b * DIM + c;
    const float4 a = *(const float4*)src;
    const float4 d = *(const float4*)(src + 4);
    o[0] = f2bf(a.x); o[1] = f2bf(a.y); o[2] = f2bf(a.z); o[3] = f2bf(a.w);
    o[4] = f2bf(d.x); o[5] = f2bf(d.y); o[6] = f2bf(d.z); o[7] = f2bf(d.w);
  }
  ((bf16x8_t*)had)[i] = o;
}

// ---------------- shared epilogue config ----------------
struct EpiCfg {
  const float* bias[3];
  float* outF[3];
  short* outB[3];
  const float* resid;
  int epi[3];
  int pos_mod[3];
  int row_off;
  int hm[3];       // head-major store flag
  int hm_L[3];     // rows per batch (grow decode)
  int hm_ltot[3];  // row stride per (b,h) in the destination
  int swz;         // XCD swizzle on/off
};

// r9-proven frag-read + MFMA step (swizzled [row][64] LDS, conflict-free).
__device__ __forceinline__ void compute_step(
    const short* As, const short* Bs, f32x4_t (&acc)[4][4],
    int wm, int wn, int lm, int lq)
{
  bf16x8_t afr[4][2], bfr[4][2];
#pragma unroll
  for (int t = 0; t < 4; ++t) {
    const int ra = wm * 64 + t * 16 + lm;
    const int rb = wn * 64 + t * 16 + lm;
    afr[t][0] = *(const bf16x8_t*)&As[ra * 64 + (((lq) ^ (ra & 7)) << 3)];
    afr[t][1] = *(const bf16x8_t*)&As[ra * 64 + (((4 + lq) ^ (ra & 7)) << 3)];
    bfr[t][0] = *(const bf16x8_t*)&Bs[rb * 64 + (((lq) ^ (rb & 7)) << 3)];
    bfr[t][1] = *(const bf16x8_t*)&Bs[rb * 64 + (((4 + lq) ^ (rb & 7)) << 3)];
  }
#pragma unroll
  for (int kk = 0; kk < 2; ++kk)
#pragma unroll
    for (int tm = 0; tm < 4; ++tm)
#pragma unroll
      for (int tn = 0; tn < 4; ++tn)
        acc[tm][tn] = __builtin_amdgcn_mfma_f32_16x16x32_bf16(
            afr[tm][kk], bfr[tn][kk], acc[tm][tn], 0, 0, 0);
}

// r9-proven hm epilogue: bias+rope -> swizzled LDS C-tile -> 8x coalesced 16-B stores.
__device__ __forceinline__ void epilogue_hm(
    short* Cs, f32x4_t (&acc)[4][4], const EpiCfg& cfg,
    int bx, int by, int wm, int wn, int lm, int lq, int tid)
{
  const int sub = bx / 7;
  const int col0 = (bx % 7) * 128;
  const int row0 = by * 128;
  const float* bias = cfg.bias[sub];
  short* outB = cfg.outB[sub];
  const int epi = cfg.epi[sub];
  const int L = cfg.hm_L[sub], ltot = cfg.hm_ltot[sub];
  int gl[4][4];
#pragma unroll
  for (int tm = 0; tm < 4; ++tm) {
    const int g = cfg.row_off + row0 + wm * 64 + tm * 16 + lq * 4;
    int bq2 = g / L;
    int l = g - bq2 * L;
#pragma unroll
    for (int r = 0; r < 4; ++r) {
      gl[tm][r] = l;
      if (++l == L) { l = 0; ++bq2; }
    }
  }
  __syncthreads();          // all frag reads of staging LDS complete
#pragma unroll
  for (int tn = 0; tn < 4; ++tn) {
    const int lc = wn * 64 + tn * 16 + lm;
    const int col = col0 + lc;
    const float bv = bias[col];
    float fr = 0.f, sgn = 0.f;
    if (epi == EPI_ROPE) {
      const int d0 = col % HD;
      fr = exp2f((float)(d0 % 56) * NEG_L2_10K_OVER_56);
      sgn = (d0 & 1) ? 1.f : -1.f;
    }
#pragma unroll
    for (int tm = 0; tm < 4; ++tm) {
#pragma unroll
      for (int r = 0; r < 4; ++r) {
        float v = acc[tm][tn][r] + bv;
        if (epi == EPI_ROPE) {
          const float prt = __shfl_xor(v, 1);   // partner col (lane^1), pre-rope
          float s, c;
          __sincosf((float)gl[tm][r] * fr, &s, &c);
          v = v * c + sgn * prt * s;
        }
        const int lr = wm * 64 + tm * 16 + lq * 4 + r;
        const int gp = (lc >> 3) ^ (((lr >> 2) & 3) << 1);
        Cs[lr * 128 + gp * 8 + (lc & 7)] = f2bf(v);
      }
    }
  }
  __syncthreads();
#pragma unroll
  for (int i = 0; i < 8; ++i) {
    const int ch = tid + 256 * i;
    const int lr = ch >> 4, g = ch & 15;
    const int phys = g ^ (((lr >> 2) & 3) << 1);
    const bf16x8_t val = *(const bf16x8_t*)&Cs[lr * 128 + phys * 8];
    const int grow = cfg.row_off + row0 + lr;
    const int bq2 = grow / L;
    const int l = grow - bq2 * L;
    const int col = col0 + g * 8;
    const int h = col / HD, d = col - h * HD;
    if (bq2 < BB)
      *(bf16x8_t*)&outB[((size_t)(bq2 * NH + h) * ltot + l) * HD + d] = val;
  }
}

// non-hm f32 epilogue (out-proj RESID, FFN RELU)
__device__ __forceinline__ void epilogue_f32(
    f32x4_t (&acc)[4][4], const EpiCfg& cfg,
    int bx, int by, int wm, int wn, int lm, int lq)
{
  const int sub = bx / 7;
  const int col0 = (bx % 7) * 128;
  const int row0 = by * 128;
  const float* bias = cfg.bias[sub];
  float* outF = cfg.outF[sub];
  short* outB = cfg.outB[sub];
  const int epi = cfg.epi[sub];
#pragma unroll
  for (int tn = 0; tn < 4; ++tn) {
    const int col = col0 + wn * 64 + tn * 16 + lm;
    const float bv = bias[col];
#pragma unroll
    for (int tm = 0; tm < 4; ++tm) {
#pragma unroll
      for (int r = 0; r < 4; ++r) {
        const int grow = cfg.row_off + row0 + wm * 64 + tm * 16 + lq * 4 + r;
        float v = acc[tm][tn][r] + bv;
        if (epi == EPI_RESID) {
          v += cfg.resid[(size_t)grow * DIM + col];
        } else if (epi == EPI_RELU) {
          v = fmaxf(v, 0.f);
        }
        if (outB) outB[(size_t)grow * DIM + col] = f2bf(v);
        else      outF[(size_t)grow * DIM + col] = v;
      }
    }
  }
}

// ======= pipelined GEMM, all problems =======
// AF32 path (r11-proven): W triple-buffered LDS via gll (issue k+2 at step k);
// A f32->regs double-set (issue k+2; cvt+ds_write k+1); per step vmcnt(12) BEFORE
// the barrier -> cross-wave safe; no vmcnt(0) drain in steady state.
// !AF32 path: both operands gll depth-1 double-buffer; issue t(k+1) -> compute(k)
// -> vmcnt(0)+barrier. Load latency hides under the 32 MFMAs (vs the old 1-phase
// which drained BEFORE compute).
// DOLN: LayerNorm fused into the A-commit (FFN).
struct ASet { float4 v[8]; };   // fixed-index only (rule #20)

__device__ __forceinline__ void a_issue(ASet& s, const float* Af, int row0,
                                        int k0, int tid)
{
#pragma unroll
  for (int j = 0; j < 4; ++j) {
    const int c = tid + 256 * j;
    const int row = c >> 3, g = c & 7;
    const float* p = Af + (size_t)(row0 + row) * DIM + k0 + g * 8;
    s.v[2 * j]     = *(const float4*)p;
    s.v[2 * j + 1] = *(const float4*)(p + 4);
  }
}
template <bool DOLN>
__device__ __forceinline__ void a_commit(const ASet& s, short* As, int tid, int k0,
                                         const float* smu, const float* srs,
                                         const float* glds, const float* blds)
{
#pragma unroll
  for (int j = 0; j < 4; ++j) {
    const int c = tid + 256 * j;
    const int row = c >> 3, g = c & 7;
    const float4 a0 = s.v[2 * j], a1 = s.v[2 * j + 1];
    float e[8] = {a0.x, a0.y, a0.z, a0.w, a1.x, a1.y, a1.z, a1.w};
    if constexpr (DOLN) {
      const float mu = smu[row], rs = srs[row];
#pragma unroll
      for (int q = 0; q < 8; ++q) {
        const int k = k0 + g * 8 + q;
        e[q] = (e[q] - mu) * rs * glds[k] + blds[k];
      }
    }
    uint4 w;
    w.x = cvt_pk_bf16(e[0], e[1]); w.y = cvt_pk_bf16(e[2], e[3]);
    w.z = cvt_pk_bf16(e[4], e[5]); w.w = cvt_pk_bf16(e[6], e[7]);
    *(uint4*)&As[row * 64 + ((g ^ (row & 7)) << 3)] = w;
  }
}
__device__ __forceinline__ void w_issue(const short* Wg, int k0, short* Wbuf,
                                        int wave, int lane)
{
#pragma unroll
  for (int j = 0; j < 4; ++j)
    gll16(Wg + (size_t)(j * 8) * DIM + k0, &Wbuf[(wave * 32 + j * 8) * 64], lane);
}

template <bool AF32, bool DOLN>
__global__ __launch_bounds__(256) void gemm_p(
    const short* __restrict__ A, const float* __restrict__ Af,
    const short* __restrict__ Wt,
    const float* __restrict__ lng, const float* __restrict__ lnb, EpiCfg cfg)
{
  __shared__ __align__(16) short lds[(AF32 ? 5 : 4) * 128 * 64];
  __shared__ float glds[DOLN ? DIM : 1], blds[DOLN ? DIM : 1];
  __shared__ float smu[DOLN ? 128 : 1], srs[DOLN ? 128 : 1];
  short* ldsA = lds;
  short* ldsW = lds + 2 * 8192;
  const int tid = threadIdx.x;
  const int wave = tid >> 6, lane = tid & 63;

  int bx = blockIdx.x, by = blockIdx.y;
  if (cfg.swz) {
    const int nx = gridDim.x;
    const int bid = blockIdx.x + blockIdx.y * nx;   // HW dispatch order
    const int xcd = bid & 7, ixd = bid >> 3;
    const int rpx = gridDim.y >> 3;                 // row panels per XCD
    bx = ixd % nx;
    by = xcd * rpx + ixd / nx;
  }
  const int sub = bx / 7;
  const int col0 = (bx % 7) * 128;
  const int row0 = by * 128;
  const int wm = wave >> 1, wn = wave & 1;
  const int lm = lane & 15, lq = lane >> 4;

  if constexpr (DOLN) {
    // LN pre-pass: per-row mean/rstd; K range == full LN row.
    for (int i = tid; i < DIM; i += 256) { glds[i] = lng[i]; blds[i] = lnb[i]; }
    const int r = tid >> 1, h = tid & 1;   // 2 threads per row, 448 elems each
    const float* rp = Af + (size_t)(row0 + r) * DIM + h * 448;
    float s = 0.f, q = 0.f;
    for (int i = 0; i < 448; i += 4) {
      const float4 v = *(const float4*)(rp + i);
      s += v.x + v.y + v.z + v.w;
      q = fmaf(v.x, v.x, fmaf(v.y, v.y, fmaf(v.z, v.z, fmaf(v.w, v.w, q))));
    }
    s += __shfl_xor(s, 1);
    q += __shfl_xor(q, 1);
    if (h == 0) {
      const float mu = s * (1.f / DIM);
      const float var = q * (1.f / DIM) - mu * mu;
      smu[r] = mu;
      srs[r] = 1.f / sqrtf(var + 1e-5f);
    }
    __syncthreads();
  }

  // staging bases: lane -> row-in-8 = lane>>3, pre-swizzled source granule
  const int sr = lane >> 3;
  const int sg = (lane & 7) ^ sr;
  const short* Wg = Wt + (size_t)(sub * DIM + col0 + wave * 32 + sr) * DIM + sg * 8;
  const short* Ag = nullptr;
  if constexpr (!AF32)
    Ag = A + (size_t)(row0 + wave * 32 + sr) * DIM + sg * 8;

  f32x4_t acc[4][4];
#pragma unroll
  for (int i = 0; i < 4; ++i)
#pragma unroll
    for (int j = 0; j < 4; ++j) acc[i][j] = (f32x4_t){0.f, 0.f, 0.f, 0.f};

  if constexpr (AF32) {
    ASet sA, sB;   // tiles: even -> sA, odd -> sB

    // prologue: issue tiles 0,1; commit tile 0
    w_issue(Wg, 0, ldsW, wave, lane);
    a_issue(sA, Af, row0, 0, tid);
    w_issue(Wg, 64, ldsW + 8192, wave, lane);
    a_issue(sB, Af, row0, 64, tid);
    asm volatile("s_waitcnt vmcnt(12)" ::: "memory");   // tile 0 done
    a_commit<DOLN>(sA, ldsA, tid, 0, smu, srs, glds, blds);
    asm volatile("s_waitcnt lgkmcnt(0)" ::: "memory");
    __builtin_amdgcn_s_barrier();
    asm volatile("" ::: "memory");

#define TSTEP(k, Sissue, Scommit, VMS)                                         \
    {                                                                          \
      if ((k) + 2 < 14) {                                                      \
        w_issue(Wg, ((k) + 2) * 64, ldsW + (((k) + 2) % 3) * 8192, wave, lane);\
        a_issue(Sissue, Af, row0, ((k) + 2) * 64, tid);                        \
      }                                                                        \
      asm volatile("s_waitcnt " VMS ::: "memory");                             \
      if ((k) + 1 < 14)                                                        \
        a_commit<DOLN>(Scommit, ldsA + (((k) + 1) & 1) * 8192, tid,            \
                       ((k) + 1) * 64, smu, srs, glds, blds);                  \
      compute_step(ldsA + ((k) & 1) * 8192, ldsW + ((k) % 3) * 8192,           \
                   acc, wm, wn, lm, lq);                                       \
      asm volatile("s_waitcnt lgkmcnt(0)" ::: "memory");                       \
      __builtin_amdgcn_s_barrier();                                            \
      asm volatile("" ::: "memory");                                           \
    }

    TSTEP(0,  sA, sB, "vmcnt(12)")
    TSTEP(1,  sB, sA, "vmcnt(12)")
    TSTEP(2,  sA, sB, "vmcnt(12)")
    TSTEP(3,  sB, sA, "vmcnt(12)")
    TSTEP(4,  sA, sB, "vmcnt(12)")
    TSTEP(5,  sB, sA, "vmcnt(12)")
    TSTEP(6,  sA, sB, "vmcnt(12)")
    TSTEP(7,  sB, sA, "vmcnt(12)")
    TSTEP(8,  sA, sB, "vmcnt(12)")
    TSTEP(9,  sB, sA, "vmcnt(12)")
    TSTEP(10, sA, sB, "vmcnt(12)")
    TSTEP(11, sB, sA, "vmcnt(12)")
    TSTEP(12, sA, sB, "vmcnt(0)")
    TSTEP(13, sB, sA, "vmcnt(0)")
#undef TSTEP
  } else {
    // prologue: stage tile 0 (both operands), drain, barrier
    w_issue(Ag, 0, ldsA, wave, lane);
    w_issue(Wg, 0, ldsW, wave, lane);
    asm volatile("s_waitcnt vmcnt(0)" ::: "memory");
    __builtin_amdgcn_s_barrier();
    asm volatile("" ::: "memory");

#define PSTEP(k)                                                               \
    {                                                                          \
      if ((k) + 1 < 14) {                                                      \
        w_issue(Ag, ((k) + 1) * 64, ldsA + (((k) + 1) & 1) * 8192, wave, lane);\
        w_issue(Wg, ((k) + 1) * 64, ldsW + (((k) + 1) & 1) * 8192, wave, lane);\
      }                                                                        \
      compute_step(ldsA + ((k) & 1) * 8192, ldsW + ((k) & 1) * 8192,           \
                   acc, wm, wn, lm, lq);                                       \
      asm volatile("s_waitcnt vmcnt(0) lgkmcnt(0)" ::: "memory");              \
      __builtin_amdgcn_s_barrier();                                            \
      asm volatile("" ::: "memory");                                           \
    }

    PSTEP(0)  PSTEP(1)  PSTEP(2)  PSTEP(3)  PSTEP(4)  PSTEP(5)  PSTEP(6)
    PSTEP(7)  PSTEP(8)  PSTEP(9)  PSTEP(10) PSTEP(11) PSTEP(12) PSTEP(13)
#undef PSTEP
  }

  if (cfg.hm[sub]) epilogue_hm(lds, acc, cfg, bx, by, wm, wn, lm, lq, tid);
  else             epilogue_f32(acc, cfg, bx, by, wm, wn, lm, lq);
}

// ---------------- attention: one 1024-thread block per (b,h) (round-1 proven) -------
#define SCP 10   // score row stride (floats): conflict-free (gcd(10,32)=2), float2-aligned

__global__ __launch_bounds__(1024, 8) void attn_kernel(
    const short* __restrict__ q, const short* __restrict__ kall,
    const short* __restrict__ vall, const float* __restrict__ gate,
    short* __restrict__ out)
{
  __shared__ __align__(16) float qs[TT * HD];        // 3584 B
  __shared__ __align__(16) float sc[NKEYS * SCP];    // 23400 B, [k][t] padded
  __shared__ float red[TT * TT * HD];                // 28672 B, [g][t][d]
  __shared__ float isum[TT];
  const int tid = threadIdx.x;
  const int bh = blockIdx.x;
  const float scale = 0.09449111825230681f;  // 1/sqrt(112)
  const float rg = tanhf(gate[0]);

  // phase 0: q -> fp32 LDS (contiguous head-major load)
  if (tid < TT * HD) qs[tid] = bf2f(q[(size_t)bh * (TT * HD) + tid]);
  __syncthreads();

  // phase 1: scores — one thread per key, contiguous 224 B key row
  if (tid < NKEYS) {
    const int k = tid;
    const short* kp = kall + ((size_t)bh * NKEYS + k) * HD;
    float dot[TT] = {};
    for (int d8 = 0; d8 < HD; d8 += 8) {
      const bf16x8_t kv8 = *(const bf16x8_t*)(kp + d8);
      float kf[8];
#pragma unroll
      for (int j = 0; j < 8; ++j) kf[j] = bf2f(kv8[j]);
#pragma unroll
      for (int t = 0; t < TT; ++t) {
        const float4 qa = *(const float4*)&qs[t * HD + d8];
        const float4 qb4 = *(const float4*)&qs[t * HD + d8 + 4];
        dot[t] = fmaf(qa.x, kf[0], dot[t]);
        dot[t] = fmaf(qa.y, kf[1], dot[t]);
        dot[t] = fmaf(qa.z, kf[2], dot[t]);
        dot[t] = fmaf(qa.w, kf[3], dot[t]);
        dot[t] = fmaf(qb4.x, kf[4], dot[t]);
        dot[t] = fmaf(qb4.y, kf[5], dot[t]);
        dot[t] = fmaf(qb4.z, kf[6], dot[t]);
        dot[t] = fmaf(qb4.w, kf[7], dot[t]);
      }
    }
    const float s = (k >= TT + KA) ? scale * rg : scale;
#pragma unroll
    for (int t = 0; t < TT; ++t) sc[k * SCP + t] = dot[t] * s;
  }
  __syncthreads();

  // phase 2: softmax per t-row, one wave per row
  const int wave = tid >> 6, lane = tid & 63;
  if (wave < TT) {
    const int t = wave;
    float m = -1e30f;
    for (int k = lane; k < NKEYS; k += 64) m = fmaxf(m, sc[k * SCP + t]);
#pragma unroll
    for (int o = 32; o >= 1; o >>= 1) m = fmaxf(m, __shfl_xor(m, o));
    float sum = 0.f;
    for (int k = lane; k < NKEYS; k += 64) {
      const float e = expf(sc[k * SCP + t] - m);
      sc[k * SCP + t] = e;
      sum += e;
    }
#pragma unroll
    for (int o = 32; o >= 1; o >>= 1) sum += __shfl_xor(sum, o);
    if (lane == 0) isum[t] = 1.f / sum;
  }
  __syncthreads();

  // phase 3: PV partials — keys split 8 ways, each thread owns (group g, dim d)
  if (tid < TT * HD) {
    const int g = tid / HD, d = tid - (tid / HD) * HD;
    const int kb = (g * NKEYS) / TT, ke = ((g + 1) * NKEYS) / TT;
    const short* vp = vall + (size_t)bh * (NKEYS * HD) + d;
    float acc[TT] = {};
    for (int k = kb; k < ke; ++k) {
      const float vv = bf2f(vp[(size_t)k * HD]);
      const float2 s0 = *(const float2*)&sc[k * SCP];
      const float2 s1 = *(const float2*)&sc[k * SCP + 2];
      const float2 s2 = *(const float2*)&sc[k * SCP + 4];
      const float2 s3 = *(const float2*)&sc[k * SCP + 6];
      acc[0] = fmaf(s0.x, vv, acc[0]);
      acc[1] = fmaf(s0.y, vv, acc[1]);
      acc[2] = fmaf(s1.x, vv, acc[2]);
      acc[3] = fmaf(s1.y, vv, acc[3]);
      acc[4] = fmaf(s2.x, vv, acc[4]);
      acc[5] = fmaf(s2.y, vv, acc[5]);
      acc[6] = fmaf(s3.x, vv, acc[6]);
      acc[7] = fmaf(s3.y, vv, acc[7]);
    }
#pragma unroll
    for (int t = 0; t < TT; ++t) red[(g * TT + t) * HD + d] = acc[t];
  }
  __syncthreads();

  // phase 4: cross-group reduce + normalize + store (row-major for out-proj)
  if (tid < TT * HD) {
    const int t = tid / HD, d = tid - (tid / HD) * HD;
    float a = 0.f;
#pragma unroll
    for (int g = 0; g < TT; ++g) a += red[(g * TT + t) * HD + d];
    out[((size_t)(bh >> 3) * TT + t) * DIM + (bh & 7) * HD + d] = f2bf(a * isum[t]);
  }
}

// ---------------- launch ----------------
extern "C" void kernel_launch(void* const* d_in, const int* in_sizes, int n_in,
                              void* d_out, int out_size, void* d_ws, size_t ws_size,
                              hipStream_t stream)
{
  const float* x   = (const float*)d_in[0];
  const float* h_a = (const float*)d_in[1];
  const float* h_t = (const float*)d_in[2];
  const float* p   = (const float*)d_in[3];
  const float* Wq  = (const float*)d_in[4];  const float* bq  = (const float*)d_in[5];
  const float* Wks = (const float*)d_in[6];  const float* bks = (const float*)d_in[7];
  const float* Wvs = (const float*)d_in[8];  const float* bvs = (const float*)d_in[9];
  const float* Wka = (const float*)d_in[10]; const float* bka = (const float*)d_in[11];
  const float* Wva = (const float*)d_in[12]; const float* bva = (const float*)d_in[13];
  const float* Wkt = (const float*)d_in[14]; const float* bkt = (const float*)d_in[15];
  const float* Wvt = (const float*)d_in[16]; const float* bvt = (const float*)d_in[17];
  const float* Wo  = (const float*)d_in[18]; const float* bo  = (const float*)d_in[19];
  const float* Wf  = (const float*)d_in[20]; const float* bf_ = (const float*)d_in[21];
  const float* gate = (const float*)d_in[22];
  const float* ln_g = (const float*)d_in[23];
  const float* ln_b = (const float*)d_in[24];

  // ---- workspace layout (bytes) ----
  const size_t SZ_HAD = (size_t)KAPAD * DIM * 2;            // bf16
  const size_t SZ_SM  = (size_t)BB * TT * DIM * 2;          // bf16 small [512 x 896]
  const size_t SZ_KV  = (size_t)BB * NH * NKEYS * HD * 2;   // bf16 [b][h][585][112]
  const size_t SZ_WT  = (size_t)9 * DD * 2;                 // 9 weights bf16
  const size_t needed = SZ_HAD + SZ_SM * 2 + SZ_KV * 2 + SZ_WT
                        + (size_t)BB * TT * DIM * 4;        // + yb fp32
  if (ws_size < needed) return;  // fail loud, not UB

  char* wsp = (char*)d_ws;
  short* hadb = (short*)wsp; wsp += SZ_HAD;
  short* qb   = (short*)wsp; wsp += SZ_SM;   // head-major [b][h][8][112]
  short* kall = (short*)wsp; wsp += SZ_KV;   // head-major [b][h][585][112]
  short* vall = (short*)wsp; wsp += SZ_KV;
  short* WtA  = (short*)wsp; wsp += SZ_WT;
  short* attn_outb = (short*)wsp; wsp += SZ_SM;
  float* yb   = (float*)wsp; wsp += (size_t)BB * TT * DIM * 4;

  dim3 blk(256);

  // 0) transpose all 9 weights -> bf16 [n][k], concatenated
  W9 w9; const float* Ws[9] = {Wq, Wks, Wvs, Wka, Wva, Wkt, Wvt, Wo, Wf};
  for (int i = 0; i < 9; ++i) w9.w[i] = Ws[i];
  wtrans<<<dim3(28, 28, 9), blk, 0, stream>>>(w9, WtA);

  // 1) h_ad -> bf16
  build_had<<<(KAPAD * DIM / 8 + 255) / 256, blk, 0, stream>>>(h_a, p, hadb);

  // 2) fused S-group GEMM (pipelined): [q | k_s | v_s] = x(f32) @ [Wq|Wks|Wvs]
  {
    EpiCfg c = {};
    c.bias[0] = bq;  c.outB[0] = qb;   c.epi[0] = EPI_ROPE; c.pos_mod[0] = TT;
    c.hm[0] = 1; c.hm_L[0] = TT; c.hm_ltot[0] = TT;
    c.bias[1] = bks; c.outB[1] = kall; c.epi[1] = EPI_ROPE; c.pos_mod[1] = TT;
    c.hm[1] = 1; c.hm_L[1] = TT; c.hm_ltot[1] = NKEYS;
    c.bias[2] = bvs; c.outB[2] = vall; c.epi[2] = EPI_NONE; c.pos_mod[2] = 1;
    c.hm[2] = 1; c.hm_L[2] = TT; c.hm_ltot[2] = NKEYS;
    gemm_p<true, false><<<dim3(21, BB * TT / 128), blk, 0, stream>>>(
        nullptr, x, WtA, nullptr, nullptr, c);
  }
  // 3) fused A-group GEMM (pipelined bf16-A): [k_a | v_a] = hadb @ [Wka|Wva]
  {
    EpiCfg c = {};
    c.bias[0] = bka; c.outB[0] = kall + (size_t)TT * HD; c.epi[0] = EPI_ROPE;
    c.pos_mod[0] = KA; c.hm[0] = 1; c.hm_L[0] = KA; c.hm_ltot[0] = NKEYS;
    c.bias[1] = bva; c.outB[1] = vall + (size_t)TT * HD; c.epi[1] = EPI_NONE;
    c.pos_mod[1] = 1; c.hm[1] = 1; c.hm_L[1] = KA; c.hm_ltot[1] = NKEYS;
    gemm_p<false, false><<<dim3(14, KAPAD / 128), blk, 0, stream>>>(
        hadb, nullptr, WtA + (size_t)3 * DD, nullptr, nullptr, c);
  }
  // 4) T-group GEMM (pipelined), XCD-swizzled (gridDim.y=256, %8==0)
  {
    EpiCfg c = {};
    c.bias[0] = bkt; c.outB[0] = kall + (size_t)(TT + KA) * HD; c.epi[0] = EPI_ROPE;
    c.pos_mod[0] = KT; c.hm[0] = 1; c.hm_L[0] = KT; c.hm_ltot[0] = NKEYS;
    c.bias[1] = bvt; c.outB[1] = vall + (size_t)(TT + KA) * HD; c.epi[1] = EPI_NONE;
    c.pos_mod[1] = 1; c.hm[1] = 1; c.hm_L[1] = KT; c.hm_ltot[1] = NKEYS;
    c.row_off = 0;
    c.swz = 1;
    gemm_p<true, false><<<dim3(14, BB * KT / 128), blk, 0, stream>>>(
        nullptr, h_t, WtA + (size_t)5 * DD, nullptr, nullptr, c);
  }

  // 5) attention — proven kernel, 1024 threads/block
  attn_kernel<<<BB * NH, dim3(1024), 0, stream>>>(qb, kall, vall, gate, attn_outb);

  // 6) out-proj + residual (fp32 out), pipelined bf16-A
  {
    EpiCfg c = {};
    c.bias[0] = bo; c.outF[0] = yb; c.epi[0] = EPI_RESID; c.pos_mod[0] = 1;
    c.resid = x;
    gemm_p<false, false><<<dim3(7, BB * TT / 128), blk, 0, stream>>>(
        attn_outb, nullptr, WtA + (size_t)7 * DD, nullptr, nullptr, c);
  }
  // 7) FFN with fused LayerNorm + ReLU (fp32 d_out), pipelined f32-A
  {
    EpiCfg c = {};
    c.bias[0] = bf_; c.outF[0] = (float*)d_out; c.epi[0] = EPI_RELU; c.pos_mod[0] = 1;
    gemm_p<true, true><<<dim3(7, BB * TT / 128), blk, 0, stream>>>(
        nullptr, yb, WtA + (size_t)8 * DD, ln_g, ln_b, c);
  }
}